// Round 11
// baseline (103.072 us; speedup 1.0000x reference)
//
#include <hip/hip_runtime.h>

// Problem shape: E=524288, IN=256, OUT=256, T=16
//   y[t] = x_j[t] @ W[t]       (tiny compute: W is 4 MB total)
//   out[e] = y[edge_types[e]]  (memory-bound gather: 512 MB fp32 writes)
//
// R10 post-mortem: halving streams 8192->4096 gave -1 us (weak positive).
// Continue the occupancy sweep: R11 = same champion structure, 512 blocks
// = 2048 waves (8 waves/CU, 2/SIMD), 4 spans per wave. Unroll-8 keeps 8
// independent LDS->store chains in flight, so latency hiding holds.

#define RL_IN  256
#define RL_OUT 256
#define RL_T   16

typedef float f32x4 __attribute__((ext_vector_type(4)));

// ---------------------------------------------------------------------------
// Kernel A (fused): y[t][o] = sum_i x[t][i] * W[t][i][o].
// 16 blocks x 1024 threads; thread (c,o) sums 64 i's; LDS reduce over c.
// ---------------------------------------------------------------------------
__global__ __launch_bounds__(1024)
void rl_compute_y(const float* __restrict__ x,
                  const float* __restrict__ W,
                  float* __restrict__ y) {
    const int t = blockIdx.x;            // 0..15
    const int c = threadIdx.x >> 8;      // 0..3
    const int o = threadIdx.x & 255;     // 0..255
    const int i0 = c * 64;

    __shared__ float xs[RL_IN];
    if (threadIdx.x < RL_IN) xs[threadIdx.x] = x[t * RL_IN + threadIdx.x];
    __syncthreads();

    const float* Wt = W + (size_t)t * RL_IN * RL_OUT + (size_t)i0 * RL_OUT;
    float acc = 0.0f;
#pragma unroll 8
    for (int i = 0; i < 64; ++i) {
        acc += xs[i0 + i] * Wt[i * RL_OUT + o];
    }

    __shared__ float part[4][RL_OUT];
    part[c][o] = acc;
    __syncthreads();
    if (c == 0) {
        y[t * RL_OUT + o] = part[0][o] + part[1][o] + part[2][o] + part[3][o];
    }
}

// ---------------------------------------------------------------------------
// Kernel B: gather (R5 structure). One wave owns a contiguous 64-row (64 KB)
// span per loop iteration. Prologue: one coalesced 256 B et burst -> LDS.
// Steady state: 64 independent 1 KB nt stores; type lookup = wave-uniform
// LDS broadcast.
// ---------------------------------------------------------------------------
__global__ __launch_bounds__(256)
void rl_gather(const int* __restrict__ et,    // [E]
               const f32x4* __restrict__ y4,  // [T*64]
               f32x4* __restrict__ out4,      // [E*64]
               int E) {
    __shared__ f32x4 ys[RL_T * (RL_OUT / 4)];  // 1024 * 16B = 16 KB
    __shared__ int tys[256];                   // per-thread type slot

    for (int i = threadIdx.x; i < RL_T * (RL_OUT / 4); i += blockDim.x)
        ys[i] = y4[i];
    __syncthreads();

    const int lane       = threadIdx.x & 63;
    const int waveBase   = threadIdx.x & ~63;   // LDS base for this wave's types
    const int wave       = blockIdx.x * (blockDim.x >> 6) + (threadIdx.x >> 6);
    const int totalWaves = gridDim.x * (blockDim.x >> 6);

    for (long base = (long)wave * 64; base < E; base += (long)totalWaves * 64) {
        // one coalesced 256 B read per wave; parked in LDS (same-wave use,
        // no barrier needed -- compiler inserts lgkmcnt waits)
        tys[waveBase + lane] = et[base + lane];

        if (base + 64 <= E) {
#pragma unroll 8
            for (int r = 0; r < 64; ++r) {
                const int t = tys[waveBase + r];        // uniform broadcast
                __builtin_nontemporal_store(
                    ys[t * 64 + lane], &out4[(size_t)(base + r) * 64 + lane]);
            }
        } else {
            for (int r = 0; base + r < E; ++r) {
                const int t = tys[waveBase + r];
                __builtin_nontemporal_store(
                    ys[t * 64 + lane], &out4[(size_t)(base + r) * 64 + lane]);
            }
        }
    }
}

extern "C" void kernel_launch(void* const* d_in, const int* in_sizes, int n_in,
                              void* d_out, int out_size, void* d_ws, size_t ws_size,
                              hipStream_t stream) {
    const float* x_j  = (const float*)d_in[0];   // [E, IN] (first T rows used)
    const float* W    = (const float*)d_in[1];   // [T, IN, OUT]
    const int*   et   = (const int*)d_in[2];     // [E]
    float*       out  = (float*)d_out;           // [E, OUT]

    const int E = in_sizes[2];                   // 524288

    float* y = (float*)d_ws;                     // [T, OUT] = 16 KB scratch

    rl_compute_y<<<RL_T, 1024, 0, stream>>>(x_j, W, y);

    // 512 blocks x 4 waves = 2048 waves (8 waves/CU, 2/SIMD); 4 spans/wave.
    rl_gather<<<512, 256, 0, stream>>>(et, (const f32x4*)y,
                                       (f32x4*)out, E);
}

// Round 12
// 102.479 us; speedup vs baseline: 1.0058x; 1.0058x over previous
//
#include <hip/hip_runtime.h>

// Problem shape: E=524288, IN=256, OUT=256, T=16
//   y[t] = x_j[t] @ W[t]       (tiny compute: W is 4 MB total)
//   out[e] = y[edge_types[e]]  (memory-bound gather: 512 MB fp32 writes)
//
// FINAL (champion = R10 config, 102.48 us):
//   - kernel A: fused per-type matvec, 16 blocks x 1024 threads, ~3.5 us
//   - kernel B: one wave per contiguous 64-row (64 KB) span; et burst to
//     LDS; 64 independent 1 KB nontemporal dwordx4 stores; 1024 blocks
//     (4096 waves, 16/CU — measured optimum of the occupancy sweep).
// Exhausted axes (all null or regressions): granule 1K-512K, nt vs plain
// (nt +5us), store dependency (LDS vs register+ballot), chip-wide window
// sweep (-12us), occupancy 8-32 waves/CU (flat +-1us). Gather pinned at
// ~5.4 TB/s = this op's indexed-row-scatter ceiling at 512 MB dispatch.

#define RL_IN  256
#define RL_OUT 256
#define RL_T   16

typedef float f32x4 __attribute__((ext_vector_type(4)));

// ---------------------------------------------------------------------------
// Kernel A (fused): y[t][o] = sum_i x[t][i] * W[t][i][o].
// 16 blocks x 1024 threads; thread (c,o) sums 64 i's; LDS reduce over c.
// ---------------------------------------------------------------------------
__global__ __launch_bounds__(1024)
void rl_compute_y(const float* __restrict__ x,
                  const float* __restrict__ W,
                  float* __restrict__ y) {
    const int t = blockIdx.x;            // 0..15
    const int c = threadIdx.x >> 8;      // 0..3
    const int o = threadIdx.x & 255;     // 0..255
    const int i0 = c * 64;

    __shared__ float xs[RL_IN];
    if (threadIdx.x < RL_IN) xs[threadIdx.x] = x[t * RL_IN + threadIdx.x];
    __syncthreads();

    const float* Wt = W + (size_t)t * RL_IN * RL_OUT + (size_t)i0 * RL_OUT;
    float acc = 0.0f;
#pragma unroll 8
    for (int i = 0; i < 64; ++i) {
        acc += xs[i0 + i] * Wt[i * RL_OUT + o];
    }

    __shared__ float part[4][RL_OUT];
    part[c][o] = acc;
    __syncthreads();
    if (c == 0) {
        y[t * RL_OUT + o] = part[0][o] + part[1][o] + part[2][o] + part[3][o];
    }
}

// ---------------------------------------------------------------------------
// Kernel B: gather. One wave owns a contiguous 64-row (64 KB) span per loop
// iteration. Prologue: one coalesced 256 B et burst -> LDS. Steady state:
// 64 independent 1 KB nt stores; type lookup = wave-uniform LDS broadcast.
// ---------------------------------------------------------------------------
__global__ __launch_bounds__(256)
void rl_gather(const int* __restrict__ et,    // [E]
               const f32x4* __restrict__ y4,  // [T*64]
               f32x4* __restrict__ out4,      // [E*64]
               int E) {
    __shared__ f32x4 ys[RL_T * (RL_OUT / 4)];  // 1024 * 16B = 16 KB
    __shared__ int tys[256];                   // per-thread type slot

    for (int i = threadIdx.x; i < RL_T * (RL_OUT / 4); i += blockDim.x)
        ys[i] = y4[i];
    __syncthreads();

    const int lane       = threadIdx.x & 63;
    const int waveBase   = threadIdx.x & ~63;   // LDS base for this wave's types
    const int wave       = blockIdx.x * (blockDim.x >> 6) + (threadIdx.x >> 6);
    const int totalWaves = gridDim.x * (blockDim.x >> 6);

    for (long base = (long)wave * 64; base < E; base += (long)totalWaves * 64) {
        // one coalesced 256 B read per wave; parked in LDS (same-wave use,
        // no barrier needed -- compiler inserts lgkmcnt waits)
        tys[waveBase + lane] = et[base + lane];

        if (base + 64 <= E) {
#pragma unroll 8
            for (int r = 0; r < 64; ++r) {
                const int t = tys[waveBase + r];        // uniform broadcast
                __builtin_nontemporal_store(
                    ys[t * 64 + lane], &out4[(size_t)(base + r) * 64 + lane]);
            }
        } else {
            for (int r = 0; base + r < E; ++r) {
                const int t = tys[waveBase + r];
                __builtin_nontemporal_store(
                    ys[t * 64 + lane], &out4[(size_t)(base + r) * 64 + lane]);
            }
        }
    }
}

extern "C" void kernel_launch(void* const* d_in, const int* in_sizes, int n_in,
                              void* d_out, int out_size, void* d_ws, size_t ws_size,
                              hipStream_t stream) {
    const float* x_j  = (const float*)d_in[0];   // [E, IN] (first T rows used)
    const float* W    = (const float*)d_in[1];   // [T, IN, OUT]
    const int*   et   = (const int*)d_in[2];     // [E]
    float*       out  = (float*)d_out;           // [E, OUT]

    const int E = in_sizes[2];                   // 524288

    float* y = (float*)d_ws;                     // [T, OUT] = 16 KB scratch

    rl_compute_y<<<RL_T, 1024, 0, stream>>>(x_j, W, y);

    // 1024 blocks x 4 waves = 4096 waves (16 waves/CU) — occupancy-sweep
    // optimum; each wave covers 2 spans.
    rl_gather<<<1024, 256, 0, stream>>>(et, (const f32x4*)y,
                                        (f32x4*)out, E);
}